// Round 4
// baseline (127.906 us; speedup 1.0000x reference)
//
#include <hip/hip_runtime.h>
#include <stdint.h>

// B=256, T=512, f32. v9 = v8 + (a) coalesced output stores: out-tile staged in
// the dead y LDS buffer, written as 6 global_store_dwordx4 instead of 23
// scattered dwords; (b) split waits: conv/onehot A-fragments are built after
// s_waitcnt vmcnt(9) (y landed) while the 9 weight gll loads are still in
// flight; only the MFMAs wait for vmcnt(0)+s_barrier. Weight staging split
// uniformly (528 chunks/wave). 16 tokens/wave, 2048 blocks, 2 blocks/CU.
#define NTOK (256 * 512)
#define TPB 256

typedef short bf16x8 __attribute__((ext_vector_type(8)));
typedef float f32x4 __attribute__((ext_vector_type(4)));
typedef unsigned short u16;
typedef unsigned int u32;

#define B1_U16 10752   // 28 chunks * 48 cols * 8 u16
#define B2_U16 6144    // 8 chunks * 96 cols * 8 u16
#define YB_U16 2816    // 5632 B per-wave y tile (reused as out-staging)
#define H_U16 1024     // 2 KB per-wave H buffer

__device__ __forceinline__ u16 f2bf(float f) {
    u32 u = __float_as_uint(f);
    return (u16)((u + 0x7fffu + ((u >> 16) & 1u)) >> 16);  // rne
}
__device__ __forceinline__ u32 cvtpk(float lo, float hi) {
    u32 r;
    asm("v_cvt_pk_bf16_f32 %0, %1, %2" : "=v"(r) : "v"(lo), "v"(hi));
    return r;
}
__device__ __forceinline__ void gll16(const void* g, void* l) {
    __builtin_amdgcn_global_load_lds(
        (const __attribute__((address_space(1))) void*)g,
        (__attribute__((address_space(3))) void*)l, 16, 0, 0);
}
__device__ __forceinline__ void gll4(const void* g, void* l) {
    __builtin_amdgcn_global_load_lds(
        (const __attribute__((address_space(1))) void*)g,
        (__attribute__((address_space(3))) void*)l, 4, 0, 0);
}

// ---------------- prep: build fragment-ordered bf16 weight image ----------------
__global__ __launch_bounds__(256, 1)
void prep_weights(const float* __restrict__ Wxh, const float* __restrict__ bxh,
                  const float* __restrict__ Wwh, const float* __restrict__ bwh,
                  const float* __restrict__ Wyh, const float* __restrict__ byh,
                  const float* __restrict__ Whl, const float* __restrict__ bhl,
                  u16* __restrict__ ws)
{
    int e = blockIdx.x * 256 + threadIdx.x;
    if (e < B1_U16) {
        int j = e & 7, n = (e >> 3) % 48, kc = e / 384;
        int k = kc * 8 + j;                  // k = 2*d + ch for k<176
        float v;
        if (k < 176)       v = Wyh[n * 176 + (k & 1) * 88 + (k >> 1)];
        else if (k < 192)  v = Wxh[n * 16 + (k - 176)];   // x-onehot rows
        else if (k < 208)  v = Wwh[n * 16 + (k - 192)];   // w-onehot rows
        else if (k == 208) v = bxh[n] + bwh[n] + byh[n];  // bias row
        else               v = 0.0f;
        ws[e] = f2bf(v);
    } else if (e < B1_U16 + B2_U16) {
        int e2 = e - B1_U16;
        int j = e2 & 7, dd = (e2 >> 3) % 96, kc = e2 / 768;
        int k = kc * 8 + j;
        float v = 0.0f;
        if (dd < 88) {
            if (k < 48)       v = Whl[dd * 48 + k];
            else if (k == 48) v = bhl[dd];
        }
        ws[e] = f2bf(v);
    }
}

// ---------------- main ----------------
__global__ __launch_bounds__(256, 2)
void tones_v9(const int* __restrict__ widx, const int* __restrict__ xidx,
              const float* __restrict__ y,
              const float* __restrict__ Wconv, const float* __restrict__ bconv,
              const u16* __restrict__ wsb,
              float* __restrict__ out)
{
    // [0, 16896)                weights, verbatim d_ws image (u16 units)
    // [16896 + wave*2816 ...)   per-wave y tile (1408 f32), reused for out tile
    // [28160 + wave*1024 ...)   per-wave H fragment buffer
    __shared__ __align__(16) u16 lds[32256];

    const int tid = threadIdx.x;
    const int wave = tid >> 6, lane = tid & 63;
    const int q = lane >> 4, c = lane & 15;

    const int tb = blockIdx.x * 64 + wave * 16;          // 16 tokens per wave

    // ---- idx loads first (oldest vmcnt slots; done by the vmcnt(9) wait) ----
    const int xv = xidx[tb + c];
    const int wv = widx[tb + c];

    // ---- stage this wave's y tile (contiguous 5632 B) into LDS: 7 loads ----
    u16* sYu = lds + 16896 + wave * YB_U16;
    {
        const char* yt = (const char*)(y + (size_t)tb * 88);
        char* dst = (char*)sYu;
        #pragma unroll
        for (int j = 0; j < 5; j++)
            gll16(yt + j * 1024 + lane * 16, dst + j * 1024);
        #pragma unroll
        for (int k = 0; k < 2; k++)
            gll4(yt + 5120 + k * 256 + lane * 4, dst + 5120 + k * 256);
    }

    // ---- stage weight image into LDS: 528 chunks/wave = 8 full + 1 quarter ----
    {
        const int wb = wave * 528;
        #pragma unroll
        for (int i = 0; i < 8; i++) {
            const int cb = wb + i * 64;
            gll16((const char*)wsb + (cb + lane) * 16, (char*)lds + cb * 16);
        }
        if (lane < 16) {
            const int cb = wb + 512;
            gll16((const char*)wsb + (cb + lane) * 16, (char*)lds + cb * 16);
        }
    }

    const float wc00 = Wconv[0], wc01 = Wconv[1], wc02 = Wconv[2];
    const float wc10 = Wconv[3], wc11 = Wconv[4], wc12 = Wconv[5];
    const float bc0 = bconv[0], bc1 = bconv[1];

    // ---- constant H chunks 6/7 for GEMM2 (bias one at k2=48, zeros) ----
    u16* sW = lds + 28160 + wave * H_U16;
    if (lane < 32) {
        uint4 hz = make_uint4((lane < 16) ? 0x3F80u : 0u, 0, 0, 0);
        *(uint4*)(sW + ((6 + (lane >> 4)) * 16 + (lane & 15)) * 8) = hz;
    }

    // ---- wait for y only (9 weight gll still in flight), build all A-frags ----
    asm volatile("s_waitcnt vmcnt(9)" ::: "memory");
    __builtin_amdgcn_sched_barrier(0);

    const float* yr = (const float*)sYu + c * 88;        // this lane's token row

    bf16x8 afr[7];
    #pragma unroll
    for (int ks = 0; ks < 5; ks++) {
        // conv directly in A-frag layout (d0 = 16*ks + 4q)
        const int d0 = 16 * ks + 4 * q;
        float p0 = (d0 == 0) ? 0.0f : yr[d0 - 1];
        f32x4 v4 = *(const f32x4*)(yr + d0);
        float p5 = yr[d0 + 4];                           // d0+4 <= 80 < 88
        float p[6] = {p0, v4[0], v4[1], v4[2], v4[3], p5};
        #pragma unroll
        for (int i = 0; i < 4; i++) {
            float c0 = fmaf(wc00, p[i], fmaf(wc01, p[i + 1], fmaf(wc02, p[i + 2], bc0)));
            float c1 = fmaf(wc10, p[i], fmaf(wc11, p[i + 1], fmaf(wc12, p[i + 2], bc1)));
            u32 pk = cvtpk(fmaxf(c0, 0.0f), fmaxf(c1, 0.0f));
            afr[ks][2 * i]     = (short)(pk & 0xFFFF);
            afr[ks][2 * i + 1] = (short)(pk >> 16);
        }
    }
    {   // ks=5: q<2 -> conv tail (d 80..87); q>=2 -> x-onehot dims (q-2)*8+j
        if (q < 2) {
            const int d0 = 80 + 4 * q;
            float p0 = yr[d0 - 1];
            f32x4 v4 = *(const f32x4*)(yr + d0);
            float p5 = (q == 0) ? yr[84] : 0.0f;         // right edge pad at d=87
            float p[6] = {p0, v4[0], v4[1], v4[2], v4[3], p5};
            #pragma unroll
            for (int i = 0; i < 4; i++) {
                float c0 = fmaf(wc00, p[i], fmaf(wc01, p[i + 1], fmaf(wc02, p[i + 2], bc0)));
                float c1 = fmaf(wc10, p[i], fmaf(wc11, p[i + 1], fmaf(wc12, p[i + 2], bc1)));
                u32 pk = cvtpk(fmaxf(c0, 0.0f), fmaxf(c1, 0.0f));
                afr[5][2 * i]     = (short)(pk & 0xFFFF);
                afr[5][2 * i + 1] = (short)(pk >> 16);
            }
        } else {
            const int base = (q - 2) * 8;
            #pragma unroll
            for (int j = 0; j < 8; j++)
                afr[5][j] = (short)((base + j == xv) ? 0x3F80 : 0);
        }
    }
    {   // ks=6: q<2 -> w-onehot dims q*8+j; q==2 -> bias one at j=0; q==3 -> zeros
        if (q < 2) {
            const int base = q * 8;
            #pragma unroll
            for (int j = 0; j < 8; j++)
                afr[6][j] = (short)((base + j == wv) ? 0x3F80 : 0);
        } else {
            #pragma unroll
            for (int j = 0; j < 8; j++)
                afr[6][j] = (short)((q == 2 && j == 0) ? 0x3F80 : 0);
        }
    }

    // ---- now require the full weight image: drain vmcnt, barrier ----
    __builtin_amdgcn_sched_barrier(0);
    asm volatile("s_waitcnt vmcnt(0)" ::: "memory");
    __builtin_amdgcn_s_barrier();

    // B1 frag (ks,nt) at u16 index ((ks*4+q)*48 + nt*16 + c)*8
    const u16* f1 = lds + (q * 48 + c) * 8;
    // B2 frag (ks,nt) at u16 index B1_U16 + ((ks*4+q)*96 + nt*16 + c)*8
    const u16* f2 = lds + B1_U16 + (q * 96 + c) * 8;

    f32x4 h0 = {0, 0, 0, 0}, h1 = {0, 0, 0, 0}, h2 = {0, 0, 0, 0};
    #pragma unroll
    for (int ks = 0; ks < 7; ks++) {
        bf16x8 b0 = *(const bf16x8*)(f1 + (ks * 192 +  0) * 8);
        bf16x8 b1 = *(const bf16x8*)(f1 + (ks * 192 + 16) * 8);
        bf16x8 b2 = *(const bf16x8*)(f1 + (ks * 192 + 32) * 8);
        h0 = __builtin_amdgcn_mfma_f32_16x16x32_bf16(afr[ks], b0, h0, 0, 0, 0);
        h1 = __builtin_amdgcn_mfma_f32_16x16x32_bf16(afr[ks], b1, h1, 0, 0, 0);
        h2 = __builtin_amdgcn_mfma_f32_16x16x32_bf16(afr[ks], b2, h2, 0, 0, 0);
    }

    // ---- epilogue1: relu -> bf16 H in A-frag layout in per-wave LDS ----
    #pragma unroll
    for (int r = 0; r < 4; r++) {
        const int row = q * 4 + r;   // D row = token index in tile
        sW[((0 + (c >> 3)) * 16 + row) * 8 + (c & 7)] = (u16)cvtpk(fmaxf(h0[r], 0.0f), 0.0f);
        sW[((2 + (c >> 3)) * 16 + row) * 8 + (c & 7)] = (u16)cvtpk(fmaxf(h1[r], 0.0f), 0.0f);
        sW[((4 + (c >> 3)) * 16 + row) * 8 + (c & 7)] = (u16)cvtpk(fmaxf(h2[r], 0.0f), 0.0f);
    }

    // ---- GEMM2: out[16x88] = H[16x64] * B2[64x96] ----
    f32x4 o0 = {0,0,0,0}, o1 = {0,0,0,0}, o2 = {0,0,0,0};
    f32x4 o3 = {0,0,0,0}, o4 = {0,0,0,0}, o5 = {0,0,0,0};
    #pragma unroll
    for (int ks = 0; ks < 2; ks++) {
        bf16x8 a2 = *(const bf16x8*)(sW + ((ks * 4 + q) * 16 + c) * 8);
        bf16x8 w0 = *(const bf16x8*)(f2 + (ks * 384 +  0) * 8);
        bf16x8 w1 = *(const bf16x8*)(f2 + (ks * 384 + 16) * 8);
        bf16x8 w2 = *(const bf16x8*)(f2 + (ks * 384 + 32) * 8);
        bf16x8 w3 = *(const bf16x8*)(f2 + (ks * 384 + 48) * 8);
        bf16x8 w4 = *(const bf16x8*)(f2 + (ks * 384 + 64) * 8);
        bf16x8 w5 = *(const bf16x8*)(f2 + (ks * 384 + 80) * 8);
        o0 = __builtin_amdgcn_mfma_f32_16x16x32_bf16(a2, w0, o0, 0, 0, 0);
        o1 = __builtin_amdgcn_mfma_f32_16x16x32_bf16(a2, w1, o1, 0, 0, 0);
        o2 = __builtin_amdgcn_mfma_f32_16x16x32_bf16(a2, w2, o2, 0, 0, 0);
        o3 = __builtin_amdgcn_mfma_f32_16x16x32_bf16(a2, w3, o3, 0, 0, 0);
        o4 = __builtin_amdgcn_mfma_f32_16x16x32_bf16(a2, w4, o4, 0, 0, 0);
        o5 = __builtin_amdgcn_mfma_f32_16x16x32_bf16(a2, w5, o5, 0, 0, 0);
    }

    // ---- stage out tile in the (dead) y buffer, then coalesced stores ----
    // Safe by data flow: these writes depend on o* <- MFMA <- afr <- y reads.
    float* sO = (float*)sYu;
    #pragma unroll
    for (int r = 0; r < 4; r++) {
        const int row = q * 4 + r;
        sO[row * 88 +  0 + c] = o0[r];
        sO[row * 88 + 16 + c] = o1[r];
        sO[row * 88 + 32 + c] = o2[r];
        sO[row * 88 + 48 + c] = o3[r];
        sO[row * 88 + 64 + c] = o4[r];
        if (c < 8) sO[row * 88 + 80 + c] = o5[r];
    }
    {
        const f32x4* sOv = (const f32x4*)sYu;
        f32x4* og = (f32x4*)(out + (size_t)tb * 88);     // 16B-aligned (tb%16==0)
        #pragma unroll
        for (int j = 0; j < 5; j++)
            og[j * 64 + lane] = sOv[j * 64 + lane];
        if (lane < 32)
            og[320 + lane] = sOv[320 + lane];
    }
}

extern "C" void kernel_launch(void* const* d_in, const int* in_sizes, int n_in,
                              void* d_out, int out_size, void* d_ws, size_t ws_size,
                              hipStream_t stream) {
    (void)in_sizes; (void)n_in; (void)out_size; (void)ws_size;
    u16* ws = (u16*)d_ws;
    prep_weights<<<dim3(66), dim3(TPB), 0, stream>>>(
        (const float*)d_in[3],  (const float*)d_in[4],
        (const float*)d_in[5],  (const float*)d_in[6],
        (const float*)d_in[7],  (const float*)d_in[8],
        (const float*)d_in[11], (const float*)d_in[12], ws);
    tones_v9<<<dim3(NTOK / 64), dim3(TPB), 0, stream>>>(
        (const int*)d_in[0], (const int*)d_in[1], (const float*)d_in[2],
        (const float*)d_in[9], (const float*)d_in[10], ws, (float*)d_out);
}

// Round 5
// 125.981 us; speedup vs baseline: 1.0153x; 1.0153x over previous
//
#include <hip/hip_runtime.h>
#include <stdint.h>

// B=256, T=512, f32. v10: 4 tiles (64 tokens) per wave, 512 blocks. Per block,
// the 33.8 KB fragment-ordered weight image (built by prep kernel in d_ws) is
// staged into LDS ONCE (amortized 4x vs v8); each wave double-buffers its y
// tile via global_load_lds so tile t+1's load overlaps tile t's compute. H for
// GEMM2 reuses the head of the current y buffer (dead after A-frag build;
// same-wave LDS ops are program-ordered). Waits: one counted s_waitcnt
// vmcnt(7) per tile + a single s_barrier at t=0. No sched_barrier pinning
// (v9 lesson). Scattered v8-style stores (proven). 2 blocks/CU (78.8 KB LDS).
#define NTOK (256 * 512)
#define TPB 256

typedef short bf16x8 __attribute__((ext_vector_type(8)));
typedef float f32x4 __attribute__((ext_vector_type(4)));
typedef unsigned short u16;
typedef unsigned int u32;

#define B1_U16 10752   // 28 chunks * 48 cols * 8 u16
#define B2_U16 6144    // 8 chunks * 96 cols * 8 u16
#define W_U16 (B1_U16 + B2_U16)               // 16896 u16 = 33792 B, 2112 chunks
#define YB_U16 2816                           // 5632 B y tile buffer

__device__ __forceinline__ u16 f2bf(float f) {
    u32 u = __float_as_uint(f);
    return (u16)((u + 0x7fffu + ((u >> 16) & 1u)) >> 16);  // rne
}
__device__ __forceinline__ u32 cvtpk(float lo, float hi) {
    u32 r;
    asm("v_cvt_pk_bf16_f32 %0, %1, %2" : "=v"(r) : "v"(lo), "v"(hi));
    return r;
}
__device__ __forceinline__ void gll16(const void* g, void* l) {
    __builtin_amdgcn_global_load_lds(
        (const __attribute__((address_space(1))) void*)g,
        (__attribute__((address_space(3))) void*)l, 16, 0, 0);
}
__device__ __forceinline__ void gll4(const void* g, void* l) {
    __builtin_amdgcn_global_load_lds(
        (const __attribute__((address_space(1))) void*)g,
        (__attribute__((address_space(3))) void*)l, 4, 0, 0);
}

// stage one 16-token y tile (contiguous 5632 B) into LDS: exactly 7 VMEM ops
__device__ __forceinline__ void stage_y(const float* ysrc, u16* dst_u16, int lane) {
    const char* yt = (const char*)ysrc;
    char* dst = (char*)dst_u16;
    #pragma unroll
    for (int j = 0; j < 5; j++)
        gll16(yt + j * 1024 + lane * 16, dst + j * 1024);
    #pragma unroll
    for (int k = 0; k < 2; k++)
        gll4(yt + 5120 + k * 256 + lane * 4, dst + 5120 + k * 256);
}

// ---------------- prep: build fragment-ordered bf16 weight image ----------------
__global__ __launch_bounds__(256, 1)
void prep_weights(const float* __restrict__ Wxh, const float* __restrict__ bxh,
                  const float* __restrict__ Wwh, const float* __restrict__ bwh,
                  const float* __restrict__ Wyh, const float* __restrict__ byh,
                  const float* __restrict__ Whl, const float* __restrict__ bhl,
                  u16* __restrict__ ws)
{
    int e = blockIdx.x * 256 + threadIdx.x;
    if (e < B1_U16) {
        int j = e & 7, n = (e >> 3) % 48, kc = e / 384;
        int k = kc * 8 + j;                  // k = 2*d + ch for k<176
        float v;
        if (k < 176)       v = Wyh[n * 176 + (k & 1) * 88 + (k >> 1)];
        else if (k < 192)  v = Wxh[n * 16 + (k - 176)];   // x-onehot rows
        else if (k < 208)  v = Wwh[n * 16 + (k - 192)];   // w-onehot rows
        else if (k == 208) v = bxh[n] + bwh[n] + byh[n];  // bias row
        else               v = 0.0f;
        ws[e] = f2bf(v);
    } else if (e < B1_U16 + B2_U16) {
        int e2 = e - B1_U16;
        int j = e2 & 7, dd = (e2 >> 3) % 96, kc = e2 / 768;
        int k = kc * 8 + j;
        float v = 0.0f;
        if (dd < 88) {
            if (k < 48)       v = Whl[dd * 48 + k];
            else if (k == 48) v = bhl[dd];
        }
        ws[e] = f2bf(v);
    }
}

// ---------------- per-tile compute (inlined 4x) ----------------
__device__ __forceinline__ void compute_tile(
    const u16* __restrict__ ldsw,   // weight image base in LDS
    u16* __restrict__ sb,           // this tile's y buffer; head reused for H
    float wc00, float wc01, float wc02, float wc10, float wc11, float wc12,
    float bc0, float bc1, int xv, int wv, int q, int c, int tb,
    float* __restrict__ out)
{
    const float* yr = (const float*)sb + c * 88;          // lane's token row
    const u16* f1 = ldsw + (q * 48 + c) * 8;
    const u16* f2 = ldsw + B1_U16 + (q * 96 + c) * 8;

    f32x4 h0 = {0, 0, 0, 0}, h1 = {0, 0, 0, 0}, h2 = {0, 0, 0, 0};
    #pragma unroll
    for (int ks = 0; ks < 7; ks++) {
        bf16x8 af;
        if (ks < 5) {
            const int d0 = 16 * ks + 4 * q;
            float p0 = (d0 == 0) ? 0.0f : yr[d0 - 1];
            f32x4 v4 = *(const f32x4*)(yr + d0);
            float p5 = yr[d0 + 4];                        // d0+4 <= 80 < 88
            float p[6] = {p0, v4[0], v4[1], v4[2], v4[3], p5};
            #pragma unroll
            for (int i = 0; i < 4; i++) {
                float c0 = fmaf(wc00, p[i], fmaf(wc01, p[i + 1], fmaf(wc02, p[i + 2], bc0)));
                float c1 = fmaf(wc10, p[i], fmaf(wc11, p[i + 1], fmaf(wc12, p[i + 2], bc1)));
                u32 pk = cvtpk(fmaxf(c0, 0.0f), fmaxf(c1, 0.0f));
                af[2 * i]     = (short)(pk & 0xFFFF);
                af[2 * i + 1] = (short)(pk >> 16);
            }
        } else if (ks == 5) {
            if (q < 2) {
                const int d0 = 80 + 4 * q;
                float p0 = yr[d0 - 1];
                f32x4 v4 = *(const f32x4*)(yr + d0);
                float p5 = (q == 0) ? yr[84] : 0.0f;      // right edge pad at d=87
                float p[6] = {p0, v4[0], v4[1], v4[2], v4[3], p5};
                #pragma unroll
                for (int i = 0; i < 4; i++) {
                    float c0 = fmaf(wc00, p[i], fmaf(wc01, p[i + 1], fmaf(wc02, p[i + 2], bc0)));
                    float c1 = fmaf(wc10, p[i], fmaf(wc11, p[i + 1], fmaf(wc12, p[i + 2], bc1)));
                    u32 pk = cvtpk(fmaxf(c0, 0.0f), fmaxf(c1, 0.0f));
                    af[2 * i]     = (short)(pk & 0xFFFF);
                    af[2 * i + 1] = (short)(pk >> 16);
                }
            } else {
                const int base = (q - 2) * 8;
                #pragma unroll
                for (int j = 0; j < 8; j++)
                    af[j] = (short)((base + j == xv) ? 0x3F80 : 0);
            }
        } else {
            if (q < 2) {
                const int base = q * 8;
                #pragma unroll
                for (int j = 0; j < 8; j++)
                    af[j] = (short)((base + j == wv) ? 0x3F80 : 0);
            } else {
                #pragma unroll
                for (int j = 0; j < 8; j++)
                    af[j] = (short)((q == 2 && j == 0) ? 0x3F80 : 0);
            }
        }
        bf16x8 b0 = *(const bf16x8*)(f1 + (ks * 192 +  0) * 8);
        bf16x8 b1 = *(const bf16x8*)(f1 + (ks * 192 + 16) * 8);
        bf16x8 b2 = *(const bf16x8*)(f1 + (ks * 192 + 32) * 8);
        h0 = __builtin_amdgcn_mfma_f32_16x16x32_bf16(af, b0, h0, 0, 0, 0);
        h1 = __builtin_amdgcn_mfma_f32_16x16x32_bf16(af, b1, h1, 0, 0, 0);
        h2 = __builtin_amdgcn_mfma_f32_16x16x32_bf16(af, b2, h2, 0, 0, 0);
    }

    // H in A-frag layout, reusing buffer head (y rows fully read above;
    // same-wave LDS ops execute in program order, so this is safe)
    u16* sW = sb;
    if (q < 2) {   // chunk 6: bias-one at k2=48 (j==0); chunk 7: zeros
        uint4 hz = make_uint4((q == 0) ? 0x3F80u : 0u, 0, 0, 0);
        *(uint4*)(sW + ((6 + q) * 16 + c) * 8) = hz;
    }
    #pragma unroll
    for (int r = 0; r < 4; r++) {
        const int row = q * 4 + r;   // D row = token index in tile
        sW[((0 + (c >> 3)) * 16 + row) * 8 + (c & 7)] = (u16)cvtpk(fmaxf(h0[r], 0.0f), 0.0f);
        sW[((2 + (c >> 3)) * 16 + row) * 8 + (c & 7)] = (u16)cvtpk(fmaxf(h1[r], 0.0f), 0.0f);
        sW[((4 + (c >> 3)) * 16 + row) * 8 + (c & 7)] = (u16)cvtpk(fmaxf(h2[r], 0.0f), 0.0f);
    }

    // GEMM2: out[16x88] = H[16x64] * B2[64x96]
    f32x4 o0 = {0,0,0,0}, o1 = {0,0,0,0}, o2 = {0,0,0,0};
    f32x4 o3 = {0,0,0,0}, o4 = {0,0,0,0}, o5 = {0,0,0,0};
    #pragma unroll
    for (int ks = 0; ks < 2; ks++) {
        bf16x8 a2 = *(const bf16x8*)(sW + ((ks * 4 + q) * 16 + c) * 8);
        bf16x8 w0 = *(const bf16x8*)(f2 + (ks * 384 +  0) * 8);
        bf16x8 w1 = *(const bf16x8*)(f2 + (ks * 384 + 16) * 8);
        bf16x8 w2 = *(const bf16x8*)(f2 + (ks * 384 + 32) * 8);
        bf16x8 w3 = *(const bf16x8*)(f2 + (ks * 384 + 48) * 8);
        bf16x8 w4 = *(const bf16x8*)(f2 + (ks * 384 + 64) * 8);
        bf16x8 w5 = *(const bf16x8*)(f2 + (ks * 384 + 80) * 8);
        o0 = __builtin_amdgcn_mfma_f32_16x16x32_bf16(a2, w0, o0, 0, 0, 0);
        o1 = __builtin_amdgcn_mfma_f32_16x16x32_bf16(a2, w1, o1, 0, 0, 0);
        o2 = __builtin_amdgcn_mfma_f32_16x16x32_bf16(a2, w2, o2, 0, 0, 0);
        o3 = __builtin_amdgcn_mfma_f32_16x16x32_bf16(a2, w3, o3, 0, 0, 0);
        o4 = __builtin_amdgcn_mfma_f32_16x16x32_bf16(a2, w4, o4, 0, 0, 0);
        o5 = __builtin_amdgcn_mfma_f32_16x16x32_bf16(a2, w5, o5, 0, 0, 0);
    }

    // store: D row = token (q*4+r), col d = nt*16 + c  (v8-proven pattern)
    float* orow = out + (size_t)(tb + q * 4) * 88;
    #pragma unroll
    for (int r = 0; r < 4; r++) {
        orow[r * 88 +  0 + c] = o0[r];
        orow[r * 88 + 16 + c] = o1[r];
        orow[r * 88 + 32 + c] = o2[r];
        orow[r * 88 + 48 + c] = o3[r];
        orow[r * 88 + 64 + c] = o4[r];
        if (c < 8) orow[r * 88 + 80 + c] = o5[r];
    }
}

// ---------------- main ----------------
__global__ __launch_bounds__(256, 2)
void tones_v10(const int* __restrict__ widx, const int* __restrict__ xidx,
               const float* __restrict__ y,
               const float* __restrict__ Wconv, const float* __restrict__ bconv,
               const u16* __restrict__ wsb,
               float* __restrict__ out)
{
    // [0, 16896)                          weight image (u16 units)
    // 16896 + wave*5632 + {0,2816}        per-wave y double buffer (H in head)
    __shared__ __align__(16) u16 lds[16896 + 4 * 2 * YB_U16];   // 78848 B

    const int tid = threadIdx.x;
    const int wave = tid >> 6, lane = tid & 63;
    const int q = lane >> 4, c = lane & 15;
    const int base = blockIdx.x * 256 + wave * 64;       // 64 tokens per wave

    // idx loads up front (8 VMEM; drained by the first vmcnt(7))
    int xv[4], wv[4];
    #pragma unroll
    for (int t = 0; t < 4; t++) {
        xv[t] = xidx[base + t * 16 + c];
        wv[t] = widx[base + t * 16 + c];
    }

    u16* buf0 = lds + W_U16 + wave * (2 * YB_U16);
    u16* buf1 = buf0 + YB_U16;

    // y0 (7 VMEM)
    stage_y(y + (size_t)base * 88, buf0, lane);

    // weight image: 528 chunks/wave = 8 full + 1 quarter (9 VMEM)
    {
        const int wb = wave * 528;
        #pragma unroll
        for (int i = 0; i < 8; i++) {
            const int cb = wb + i * 64;
            gll16((const char*)wsb + (cb + lane) * 16, (char*)lds + cb * 16);
        }
        if (lane < 16) {
            const int cb = wb + 512;
            gll16((const char*)wsb + (cb + lane) * 16, (char*)lds + cb * 16);
        }
    }

    // y1 prefetch (7 VMEM) — stays in flight across the t=0 wait+barrier
    stage_y(y + (size_t)(base + 16) * 88, buf1, lane);

    const float wc00 = Wconv[0], wc01 = Wconv[1], wc02 = Wconv[2];
    const float wc10 = Wconv[3], wc11 = Wconv[4], wc12 = Wconv[5];
    const float bc0 = bconv[0], bc1 = bconv[1];

    #pragma unroll
    for (int t = 0; t < 4; t++) {
        u16* sb = (t & 1) ? buf1 : buf0;
        if (t >= 1 && t < 3)   // prefetch y_{t+1} into the other buffer
            stage_y(y + (size_t)(base + (t + 1) * 16) * 88, (t & 1) ? buf0 : buf1, lane);
        // y_t guaranteed: >= 7 ops (y_{t+1} or stores) issued after it.
        // t=0 additionally drains the weight glls (y1 = the 7 allowed in flight).
        asm volatile("s_waitcnt vmcnt(7)" ::: "memory");
        if (t == 0) __builtin_amdgcn_s_barrier();        // weights visible block-wide
        compute_tile(lds, sb, wc00, wc01, wc02, wc10, wc11, wc12, bc0, bc1,
                     xv[t], wv[t], q, c, base + t * 16, out);
    }
}

extern "C" void kernel_launch(void* const* d_in, const int* in_sizes, int n_in,
                              void* d_out, int out_size, void* d_ws, size_t ws_size,
                              hipStream_t stream) {
    (void)in_sizes; (void)n_in; (void)out_size; (void)ws_size;
    u16* ws = (u16*)d_ws;
    prep_weights<<<dim3(66), dim3(TPB), 0, stream>>>(
        (const float*)d_in[3],  (const float*)d_in[4],
        (const float*)d_in[5],  (const float*)d_in[6],
        (const float*)d_in[7],  (const float*)d_in[8],
        (const float*)d_in[11], (const float*)d_in[12], ws);
    tones_v10<<<dim3(NTOK / 256), dim3(TPB), 0, stream>>>(
        (const int*)d_in[0], (const int*)d_in[1], (const float*)d_in[2],
        (const float*)d_in[9], (const float*)d_in[10], ws, (float*)d_out);
}